// Round 2
// baseline (4675.225 us; speedup 1.0000x reference)
//
#include <hip/hip_runtime.h>

// Problem constants: b=4, C=192, heads=6, ch=32, H=W=256, h2=w2=128, WS=8, SS=4, N=64

// ---------------------------------------------------------------------------
// Generic tiled fp32 GEMM: Out[b][o][p] = sum_c W[b][o][c] * X[b][c][p]
//   o-tile = 192 (X read exactly once), p-tile = 64, K-step = 16.
//   XT=true : X laid out as [b][p][c] (transposed input, for proj1)
//   EPI=0: plain   EPI=1: += X[b][o][p] (residual, O==K)   EPI=2: branch0 final
//   (adds gathered out1 contribution: window_reverse + roll(+4,+4))
// ---------------------------------------------------------------------------
template<int EPI, bool XT>
__global__ __launch_bounds__(256)
void gemm_k(const float* __restrict__ Wm, const float* __restrict__ X,
            float* __restrict__ Out, const float* __restrict__ G1,
            int K, int P, long wstride, long xstride, long ostride)
{
  const int b = blockIdx.z;
  const float* Wb = Wm + (long)b * wstride;
  const float* Xb = X  + (long)b * xstride;
  float*       Ob = Out + (long)b * ostride;
  const int p0 = blockIdx.x * 64, o0 = blockIdx.y * 192;

  __shared__ float Ws[16][204];   // 192-wide o tile, pad->204 (2-way max on store)
  __shared__ float Xs[16][68];
  const int tid = threadIdx.x;
  const int tx = tid & 15, ty = tid >> 4;
  float acc[12][4] = {};

  for (int k0 = 0; k0 < K; k0 += 16) {
    {
      const int c = tid & 15, r = tid >> 4;
      #pragma unroll
      for (int i = 0; i < 12; i++)
        Ws[c][r + 16*i] = Wb[(long)(o0 + r + 16*i) * K + k0 + c];
      if (!XT) {
        const int pp = tid & 63, rr = tid >> 6;
        #pragma unroll
        for (int i = 0; i < 4; i++)
          Xs[rr + 4*i][pp] = Xb[(long)(k0 + rr + 4*i) * P + p0 + pp];
      } else {
        const int cc = tid & 15, pr = tid >> 4;
        #pragma unroll
        for (int i = 0; i < 4; i++)
          Xs[cc][pr + 16*i] = Xb[(long)(p0 + pr + 16*i) * K + k0 + cc];
      }
    }
    __syncthreads();
    #pragma unroll
    for (int kk = 0; kk < 16; kk++) {
      const float4 xv = *(const float4*)&Xs[kk][tx*4];
      #pragma unroll
      for (int jq = 0; jq < 3; jq++) {
        const float4 a = *(const float4*)&Ws[kk][ty*12 + jq*4];
        acc[jq*4+0][0] += a.x*xv.x; acc[jq*4+0][1] += a.x*xv.y; acc[jq*4+0][2] += a.x*xv.z; acc[jq*4+0][3] += a.x*xv.w;
        acc[jq*4+1][0] += a.y*xv.x; acc[jq*4+1][1] += a.y*xv.y; acc[jq*4+1][2] += a.y*xv.z; acc[jq*4+1][3] += a.y*xv.w;
        acc[jq*4+2][0] += a.z*xv.x; acc[jq*4+2][1] += a.z*xv.y; acc[jq*4+2][2] += a.z*xv.z; acc[jq*4+2][3] += a.z*xv.w;
        acc[jq*4+3][0] += a.w*xv.x; acc[jq*4+3][1] += a.w*xv.y; acc[jq*4+3][2] += a.w*xv.z; acc[jq*4+3][3] += a.w*xv.w;
      }
    }
    __syncthreads();
  }

  #pragma unroll
  for (int i = 0; i < 12; i++) {
    const int o = o0 + ty*12 + i;
    const long base = (long)o * P + p0 + tx*4;
    float4 r = make_float4(acc[i][0], acc[i][1], acc[i][2], acc[i][3]);
    if (EPI == 1) {
      const float4 xr = *(const float4*)&Xb[base];
      r.x += xr.x; r.y += xr.y; r.z += xr.z; r.w += xr.w;
    }
    if (EPI == 2) {
      float gv[4];
      #pragma unroll
      for (int j = 0; j < 4; j++) {
        const int p  = p0 + tx*4 + j;
        const int y  = p >> 8,        x  = p & 255;
        const int yy = (y + 252) & 255, xx = (x + 252) & 255;   // roll(+4,+4)
        const int win = b*1024 + (yy>>3)*32 + (xx>>3);
        const int n   = ((yy&7)<<3) | (xx&7);
        gv[j] = G1[(long)o * 262144 + win*64 + n];
      }
      r.x += gv[0]; r.y += gv[1]; r.z += gv[2]; r.w += gv[3];
    }
    *(float4*)&Ob[base] = r;
  }
}

// ---------------------------------------------------------------------------
// Depthwise 3x3, SAME padding. grid(Hh, B*Cc), block(Ww)
// ---------------------------------------------------------------------------
__global__ void dwconv_k(const float* __restrict__ in, const float* __restrict__ wd,
                         float* __restrict__ out, int Cc, int Hh, int Ww)
{
  const int y = blockIdx.x, bc = blockIdx.y;
  const int x = threadIdx.x;
  const int c = bc % Cc;
  const float* w9 = wd + c*9;
  const float* ip = in + (long)bc * Hh * Ww;
  float s = 0.f;
  #pragma unroll
  for (int dy = 0; dy < 3; dy++) {
    const int yy = y + dy - 1;
    if (yy < 0 || yy >= Hh) continue;
    const float* row = ip + (long)yy * Ww;
    #pragma unroll
    for (int dx = 0; dx < 3; dx++) {
      const int xx = x + dx - 1;
      if (xx >= 0 && xx < Ww) s += w9[dy*3+dx] * row[xx];
    }
  }
  out[(long)bc * Hh * Ww + (long)y * Ww + x] = s;
}

// ---------------------------------------------------------------------------
// Depthwise 3x3 on the window-shuffled q1 image (16,192,128,128), gathering
// from the linear conv1x1 output (4,192,256,256). grid(128, 16*192), block(128)
// ---------------------------------------------------------------------------
__global__ void dwshuf_k(const float* __restrict__ in, const float* __restrict__ wd,
                         float* __restrict__ out)
{
  const int y1 = blockIdx.x, bc = blockIdx.y;
  const int x1 = threadIdx.x;
  const int c = bc % 192, Bp = bc / 192;
  const int bq = Bp >> 2, q3 = Bp & 3;
  const float* w9 = wd + c*9;
  const float* ip = in + ((long)bq*192 + c) * 65536;
  float s = 0.f;
  #pragma unroll
  for (int dy = 0; dy < 3; dy++) {
    const int yy = y1 + dy - 1;
    if (yy < 0 || yy >= 128) continue;
    const int hi = yy >> 3, ry = yy & 7;
    const int wy = q3*8 + (hi >> 1);
    #pragma unroll
    for (int dx = 0; dx < 3; dx++) {
      const int xx = x1 + dx - 1;
      if (xx < 0 || xx >= 128) continue;
      const int wi = xx >> 3, rx = xx & 7;
      const int wx = ((hi & 1) << 4) + wi;
      s += w9[dy*3+dx] * ip[(wy*8 + ry)*256 + wx*8 + rx];
    }
  }
  out[(long)bc * 16384 + y1*128 + x1] = s;
}

// ---------------------------------------------------------------------------
// AvgPool2d(2,2): (4,192,256,256) -> (4,192,128,128). grid(128, 768), block(128)
// ---------------------------------------------------------------------------
__global__ void avgpool_k(const float* __restrict__ in, float* __restrict__ out)
{
  const int y = blockIdx.x, bc = blockIdx.y;
  const int x = threadIdx.x;
  const float* ip = in + (long)bc*65536 + (2*y)*256 + 2*x;
  out[(long)bc*16384 + y*128 + x] = 0.25f * (ip[0] + ip[1] + ip[256] + ip[257]);
}

// ---------------------------------------------------------------------------
// Branch0 gram + sum-of-squares: G[b,h,c,d] = sum_n q[c,n]k[d,n] (split-K atomics)
// nrm[0..767] = sum q^2 per (b, h*32+c); nrm[768..1535] = sum k^2.
// grid(64, 6, 4), block(64)
// ---------------------------------------------------------------------------
__global__ __launch_bounds__(64)
void gram_k(const float* __restrict__ q, const float* __restrict__ k,
            float* __restrict__ G, float* __restrict__ nrm)
{
  const int chunk = blockIdx.x, h = blockIdx.y, b = blockIdx.z;
  const long base = ((long)b*192 + h*32) * 65536 + chunk*1024;
  __shared__ float Qs[64][36];
  __shared__ float Ks[64][36];
  const int tid = threadIdx.x;
  const int ty = tid >> 3, tx = tid & 7;
  const int cc = tid & 31;
  float acc[4][4] = {};
  float ssq = 0.f;

  for (int t = 0; t < 16; t++) {
    __syncthreads();
    #pragma unroll 8
    for (int c = 0; c < 32; c++) {
      Qs[tid][c] = q[base + (long)c*65536 + t*64 + tid];
      Ks[tid][c] = k[base + (long)c*65536 + t*64 + tid];
    }
    __syncthreads();
    {
      const float (*S)[36] = (tid < 32) ? Qs : Ks;
      float lo = 0.f;
      #pragma unroll 16
      for (int n = 0; n < 64; n++) { const float v = S[n][cc]; lo += v*v; }
      ssq += lo;
    }
    #pragma unroll 8
    for (int n = 0; n < 64; n++) {
      const float4 a = *(const float4*)&Qs[n][ty*4];
      const float4 v = *(const float4*)&Ks[n][tx*4];
      acc[0][0] += a.x*v.x; acc[0][1] += a.x*v.y; acc[0][2] += a.x*v.z; acc[0][3] += a.x*v.w;
      acc[1][0] += a.y*v.x; acc[1][1] += a.y*v.y; acc[1][2] += a.y*v.z; acc[1][3] += a.y*v.w;
      acc[2][0] += a.z*v.x; acc[2][1] += a.z*v.y; acc[2][2] += a.z*v.z; acc[2][3] += a.z*v.w;
      acc[3][0] += a.w*v.x; acc[3][1] += a.w*v.y; acc[3][2] += a.w*v.z; acc[3][3] += a.w*v.w;
    }
  }
  float* Gp = G + (long)(b*6 + h) * 1024;
  #pragma unroll
  for (int i = 0; i < 4; i++)
    #pragma unroll
    for (int j = 0; j < 4; j++)
      atomicAdd(&Gp[(ty*4 + i)*32 + tx*4 + j], acc[i][j]);
  atomicAdd(&nrm[(tid < 32 ? 0 : 768) + b*192 + h*32 + cc], ssq);
}

// ---------------------------------------------------------------------------
// Branch0 softmax over d of G/(|q||k|)*temp0. grid(24), block(32)
// ---------------------------------------------------------------------------
__global__ void softmax0_k(const float* __restrict__ G, const float* __restrict__ nrm,
                           const float* __restrict__ temp0, float* __restrict__ attn)
{
  const int bh = blockIdx.x;
  const int b = bh / 6, h = bh % 6;
  const int c = threadIdx.x;
  __shared__ float nks[32];
  nks[c] = fmaxf(sqrtf(nrm[768 + b*192 + h*32 + c]), 1e-12f);
  __syncthreads();
  const float nq = fmaxf(sqrtf(nrm[b*192 + h*32 + c]), 1e-12f);
  const float t = temp0[h];
  const float* g = G + (long)bh*1024 + c*32;
  float v[32];
  float mx = -1e30f;
  #pragma unroll
  for (int d = 0; d < 32; d++) { v[d] = g[d] / (nq * nks[d]) * t; mx = fmaxf(mx, v[d]); }
  float s = 0.f;
  #pragma unroll
  for (int d = 0; d < 32; d++) { v[d] = __expf(v[d] - mx); s += v[d]; }
  const float inv = 1.f / s;
  float* a = attn + (long)bh*1024 + c*32;
  #pragma unroll
  for (int d = 0; d < 32; d++) a[d] = v[d] * inv;
}

// ---------------------------------------------------------------------------
// M0[b,o,h*32+d] = sum_c Wproj0[o,h*32+c] * attn[b,h,c,d]. grid(192,4), block(192)
// ---------------------------------------------------------------------------
__global__ void m0_k(const float* __restrict__ Wp, const float* __restrict__ attn,
                     float* __restrict__ M0)
{
  const int o = blockIdx.x, b = blockIdx.y, m = threadIdx.x;
  const int h = m >> 5, d = m & 31;
  const float* a = attn + (long)(b*6 + h)*1024 + d;
  const float* w = Wp + (long)o*192 + h*32;
  float s = 0.f;
  #pragma unroll
  for (int c = 0; c < 32; c++) s += w[c] * a[c*32];
  M0[((long)b*192 + o)*192 + m] = s;
}

// ---------------------------------------------------------------------------
// Shifted-window cosine attention. Block = 128 thr = 2 waves per (kwin,head);
// wave w handles q-subwindows 2w and 2w+1 SIMULTANEOUSLY so every K/V
// broadcast ds_read feeds 8 FMAs (was 4), and rpb/mask/nkinv per-score
// overhead is shared. nk stored as reciprocal (kills per-score divides);
// mask via register-resident __ballot bitmask, skipped entirely for the
// 87% of kv-windows with no region boundary (mhi<15 && mwi<15).
// q1s: (16,192,128,128) shuffled q (post-dwconv); kv1d: (4,384,128,128).
// grid(1024, 6), block(128)
// ---------------------------------------------------------------------------
__global__ __launch_bounds__(128)
void wattn_k(const float* __restrict__ q1s, const float* __restrict__ kv1d,
             const float* __restrict__ rpb_table, const float* __restrict__ temp1,
             float* __restrict__ out1)
{
  const int kwin = blockIdx.x, head = blockIdx.y;
  const int tid = threadIdx.x;
  const int w = tid >> 6, lane = tid & 63;
  const int winA = kwin*4 + 2*w, winB = winA + 1;   // wiA even<=14 -> no carry

  const int qimg = winA >> 8;
  const int hiA = (winA >> 4) & 15, wiA = winA & 15;
  const int hiB = (winB >> 4) & 15, wiB = winB & 15;
  const int kb = kwin >> 8, khi = (kwin >> 4) & 15, kwi = kwin & 15;
  const int mw  = kwin & 255, mhi = mw >> 4, mwi = mw & 15;

  __shared__ float Ks[32][64];
  __shared__ float Vs[32][64];
  __shared__ float nkinv_s[64];
  __shared__ float nkp[2][64];
  __shared__ float rpbh[226];

  const int r  = lane >> 3, s_ = lane & 7;
  const int qyA = (hiA*8 + r + 4) & 127, qxA = (wiA*8 + s_ + 4) & 127;
  const int qyB = (hiB*8 + r + 4) & 127, qxB = (wiB*8 + s_ + 4) & 127;
  const int ky  = (khi*8 + r + 4) & 127, kx  = (kwi*8 + s_ + 4) & 127;

  const long qbase = ((long)qimg*192 + head*32) * 16384;
  const long kbase = ((long)kb*384  + head*32) * 16384;
  const long qoffA = (long)qyA*128 + qxA;
  const long qoffB = (long)qyB*128 + qxB;
  const long koff  = (long)ky*128 + kx;

  // cooperative K/V staging; k-norm partials for free while values are in regs
  {
    float kk = 0.f;
    #pragma unroll
    for (int i = 0; i < 16; i++) {
      const int ch = w*16 + i;
      const float kvl = kv1d[kbase + (long)ch*16384 + koff];
      Ks[ch][lane] = kvl;
      kk += kvl*kvl;
      Vs[ch][lane] = kv1d[kbase + (long)(192 + ch)*16384 + koff];
    }
    nkp[w][lane] = kk;
  }
  for (int i = tid; i < 225; i += 128) rpbh[i] = rpb_table[i*6 + head];

  // mask bitmask: register-only, identical in both waves. bit m set <=> same region.
  const bool edge = (mhi == 15) || (mwi == 15);
  unsigned long long bm = ~0ull;
  if (edge) {
    const int gy = mhi*8 + r, gx = mwi*8 + s_;
    const int yid = (gy < 120) ? 0 : ((gy < 124) ? 1 : 2);
    const int xid = (gx < 120) ? 0 : ((gx < 124) ? 1 : 2);
    const int myc = yid*3 + xid;
    #pragma unroll
    for (int g = 0; g < 9; g++) {
      const unsigned long long mgm = __ballot(myc == g);
      if (myc == g) bm = mgm;
    }
  }

  __syncthreads();   // Ks/Vs/nkp visible

  if (tid < 64)
    nkinv_s[lane] = 1.f / fmaxf(sqrtf(nkp[0][lane] + nkp[1][lane]), 1e-12f);

  // QK^T for both windows; q loaded in halves to cap register pressure
  float scA[64], scB[64];
  #pragma unroll
  for (int m = 0; m < 64; m++) { scA[m] = 0.f; scB[m] = 0.f; }
  float nqA = 0.f, nqB = 0.f;
  #pragma unroll
  for (int half = 0; half < 2; half++) {
    float qA[16], qB[16];
    #pragma unroll
    for (int i = 0; i < 16; i++) {
      const long co = (long)(half*16 + i)*16384;
      qA[i] = q1s[qbase + co + qoffA];
      qB[i] = q1s[qbase + co + qoffB];
      nqA += qA[i]*qA[i];
      nqB += qB[i]*qB[i];
    }
    #pragma unroll
    for (int i = 0; i < 16; i++) {
      const int ch = half*16 + i;
      #pragma unroll
      for (int mg = 0; mg < 16; mg++) {
        const float4 k4 = *(const float4*)&Ks[ch][mg*4];
        scA[mg*4+0] += qA[i]*k4.x; scA[mg*4+1] += qA[i]*k4.y;
        scA[mg*4+2] += qA[i]*k4.z; scA[mg*4+3] += qA[i]*k4.w;
        scB[mg*4+0] += qB[i]*k4.x; scB[mg*4+1] += qB[i]*k4.y;
        scB[mg*4+2] += qB[i]*k4.z; scB[mg*4+3] += qB[i]*k4.w;
      }
    }
  }

  __syncthreads();   // nkinv_s ready

  const float tmp = temp1[head];
  const float sA = tmp / fmaxf(sqrtf(nqA), 1e-12f);
  const float sB = tmp / fmaxf(sqrtf(nqB), 1e-12f);
  const int ib = (r + 7)*15 + (s_ + 7);
  if (edge) {
    #pragma unroll
    for (int m = 0; m < 64; m++) {
      const int rm = m >> 3, sm = m & 7;
      float u = rpbh[ib - rm*15 - sm];
      u += ((bm >> m) & 1ull) ? 0.f : -100.f;
      const float t = nkinv_s[m];
      scA[m] = scA[m]*t*sA + u;
      scB[m] = scB[m]*t*sB + u;
    }
  } else {
    #pragma unroll
    for (int m = 0; m < 64; m++) {
      const int rm = m >> 3, sm = m & 7;
      const float u = rpbh[ib - rm*15 - sm];
      const float t = nkinv_s[m];
      scA[m] = scA[m]*t*sA + u;
      scB[m] = scB[m]*t*sB + u;
    }
  }

  float mxA = scA[0], mxB = scB[0];
  #pragma unroll
  for (int m = 1; m < 64; m++) { mxA = fmaxf(mxA, scA[m]); mxB = fmaxf(mxB, scB[m]); }
  float suA = 0.f, suB = 0.f;
  #pragma unroll
  for (int m = 0; m < 64; m++) {
    scA[m] = __expf(scA[m] - mxA); suA += scA[m];
    scB[m] = __expf(scB[m] - mxB); suB += scB[m];
  }
  const float ivA = 1.f / suA, ivB = 1.f / suB;

  // PV: each V broadcast read feeds both windows
  float* opA = out1 + ((long)winA*64 + lane)*192 + head*32;
  float* opB = out1 + ((long)winB*64 + lane)*192 + head*32;
  #pragma unroll
  for (int g = 0; g < 8; g++) {
    float oA[4], oB[4];
    #pragma unroll
    for (int cc = 0; cc < 4; cc++) {
      const int ch = g*4 + cc;
      float aA = 0.f, aB = 0.f;
      #pragma unroll
      for (int mg = 0; mg < 16; mg++) {
        const float4 v4 = *(const float4*)&Vs[ch][mg*4];
        aA += scA[mg*4+0]*v4.x + scA[mg*4+1]*v4.y + scA[mg*4+2]*v4.z + scA[mg*4+3]*v4.w;
        aB += scB[mg*4+0]*v4.x + scB[mg*4+1]*v4.y + scB[mg*4+2]*v4.z + scB[mg*4+3]*v4.w;
      }
      oA[cc] = aA * ivA;
      oB[cc] = aB * ivB;
    }
    *(float4*)&opA[g*4] = make_float4(oA[0], oA[1], oA[2], oA[3]);
    *(float4*)&opB[g*4] = make_float4(oB[0], oB[1], oB[2], oB[3]);
  }
}

// ---------------------------------------------------------------------------
// Buffer lifetime map:
//   U1: conv scratch -> kv1_lin(S3)+kv1d(S4) -> out1w
//   U2: q0_dw -> v0_dw (LIVE until final GEMM)
//   U3: xds(S1)+xds2(S2) -> q1s
//   d_out: q1_lin -> out1pre -> final output
// KV path runs BEFORE dwshuf so S2 is consumed before q1s overwrites U3.
// ---------------------------------------------------------------------------
extern "C" void kernel_launch(void* const* d_in, const int* in_sizes, int n_in,
                              void* d_out, int out_size, void* d_ws, size_t ws_size,
                              hipStream_t stream)
{
  (void)in_sizes; (void)n_in; (void)out_size; (void)ws_size;
  const float* x      = (const float*)d_in[0];
  const float* Wq0    = (const float*)d_in[1];
  const float* Wqdw0  = (const float*)d_in[2];
  const float* Wkv0   = (const float*)d_in[3];
  const float* Wkvdw0 = (const float*)d_in[4];
  const float* Wq1    = (const float*)d_in[5];
  const float* Wqdw1  = (const float*)d_in[6];
  const float* Wkv1   = (const float*)d_in[7];
  const float* Wkvdw1 = (const float*)d_in[8];
  const float* Wproj0 = (const float*)d_in[9];
  const float* Wproj1 = (const float*)d_in[10];
  const float* temp0  = (const float*)d_in[11];
  const float* temp1  = (const float*)d_in[12];
  const float* rpbt   = (const float*)d_in[13];
  const float* Wds    = (const float*)d_in[14];

  char* ws = (char*)d_ws;
  const long UB = 201326592L;              // 4*192*65536*4 bytes
  float* U1 = (float*)(ws);
  float* U2 = (float*)(ws + UB);
  float* U3 = (float*)(ws + 2*UB);
  char* tiny = ws + 3*UB;
  float* G     = (float*)(tiny);           // 4*6*32*32
  float* nrm   = (float*)(tiny + 98304);   // 2*768
  float* attn0 = (float*)(tiny + 104448);  // 4*6*32*32
  float* M0    = (float*)(tiny + 202752);  // 4*192*192

  float* S1   = U3;                                  // xds   (4,192,128,128)
  float* S2   = (float*)((char*)U3 + 50331648);      // xds2
  float* S3   = U1;                                  // kv1_lin (4,384,128,128)
  float* S4   = (float*)((char*)U1 + 100663296);     // kv1d
  float* q1lin = (float*)d_out;                      // (4,192,256,256) scratch
  float* q1s  = U3;                                  // (16,192,128,128) after S1/S2 dead
  float* out1pre = (float*)d_out;                    // (4096*64,192) scratch in d_out
  float* out1w   = U1;                               // (192, 262144) after S3/S4 dead

  const long XS  = 192L * 65536;
  const long XS2 = 192L * 16384;

  // ---- branch 0 ----
  gemm_k<0,false><<<dim3(1024,1,4), 256, 0, stream>>>(Wq0, x, U1, nullptr, 192, 65536, 0L, XS, XS);
  dwconv_k<<<dim3(256,768), 256, 0, stream>>>(U1, Wqdw0, U2, 192, 256, 256);            // q0_dw -> U2
  gemm_k<0,false><<<dim3(1024,1,4), 256, 0, stream>>>(Wkv0, x, U1, nullptr, 192, 65536, 0L, XS, XS);
  dwconv_k<<<dim3(256,768), 256, 0, stream>>>(U1, Wkvdw0, U3, 192, 256, 256);           // k0_dw -> U3
  hipMemsetAsync(G, 0, 104448, stream);                                                 // G + nrm
  gram_k<<<dim3(64,6,4), 64, 0, stream>>>(U2, U3, G, nrm);
  softmax0_k<<<24, 32, 0, stream>>>(G, nrm, temp0, attn0);
  m0_k<<<dim3(192,4), 192, 0, stream>>>(Wproj0, attn0, M0);
  gemm_k<0,false><<<dim3(1024,1,4), 256, 0, stream>>>(Wkv0 + 192*192, x, U1, nullptr, 192, 65536, 0L, XS, XS);
  dwconv_k<<<dim3(256,768), 256, 0, stream>>>(U1, Wkvdw0 + 192*9, U2, 192, 256, 256);   // v0_dw -> U2 (live to end)

  // ---- branch 1: KV path first (consumes S2 before q1s overwrites U3) ----
  avgpool_k<<<dim3(128,768), 128, 0, stream>>>(x, S1);
  gemm_k<1,false><<<dim3(256,1,4), 256, 0, stream>>>(Wds, S1, S2, nullptr, 192, 16384, 0L, XS2, XS2);
  gemm_k<0,false><<<dim3(256,2,4), 256, 0, stream>>>(Wkv1, S2, S3, nullptr, 192, 16384, 0L, XS2, 384L*16384);
  dwconv_k<<<dim3(128,1536), 128, 0, stream>>>(S3, Wkvdw1, S4, 384, 128, 128);           // kv1d -> S4

  // ---- branch 1: Q path ----
  gemm_k<0,false><<<dim3(1024,1,4), 256, 0, stream>>>(Wq1, x, q1lin, nullptr, 192, 65536, 0L, XS, XS);
  dwshuf_k<<<dim3(128,3072), 128, 0, stream>>>(q1lin, Wqdw1, q1s);                        // q1s -> U3 (full)
  wattn_k<<<dim3(1024,6), 128, 0, stream>>>(q1s, S4, rpbt, temp1, out1pre);               // -> d_out
  gemm_k<0,true><<<dim3(4096,1,1), 256, 0, stream>>>(Wproj1, out1pre, out1w, nullptr, 192, 262144, 0L, 0L, 0L);

  // ---- final: out = M0 @ v0_dw + gathered out1 ----
  gemm_k<2,false><<<dim3(1024,1,4), 256, 0, stream>>>(M0, U2, (float*)d_out, out1w, 192, 65536, 36864L, XS, XS);
}

// Round 3
// 4123.920 us; speedup vs baseline: 1.1337x; 1.1337x over previous
//
#include <hip/hip_runtime.h>

// Problem constants: b=4, C=192, heads=6, ch=32, H=W=256, h2=w2=128, WS=8, SS=4, N=64

// ---------------------------------------------------------------------------
// Generic tiled fp32 GEMM: Out[b][o][p] = sum_c W[b][o][c] * X[b][c][p]
//   o-tile = 192 (X read exactly once), p-tile = 64, K-step = 16.
//   XT=true : X laid out as [b][p][c] (transposed input, for proj1)
//   EPI=0: plain   EPI=1: += X[b][o][p] (residual, O==K)   EPI=2: branch0 final
//   (adds gathered out1 contribution: window_reverse + roll(+4,+4))
// ---------------------------------------------------------------------------
template<int EPI, bool XT>
__global__ __launch_bounds__(256)
void gemm_k(const float* __restrict__ Wm, const float* __restrict__ X,
            float* __restrict__ Out, const float* __restrict__ G1,
            int K, int P, long wstride, long xstride, long ostride)
{
  const int b = blockIdx.z;
  const float* Wb = Wm + (long)b * wstride;
  const float* Xb = X  + (long)b * xstride;
  float*       Ob = Out + (long)b * ostride;
  const int p0 = blockIdx.x * 64, o0 = blockIdx.y * 192;

  __shared__ float Ws[16][204];   // 192-wide o tile, pad->204 (2-way max on store)
  __shared__ float Xs[16][68];
  const int tid = threadIdx.x;
  const int tx = tid & 15, ty = tid >> 4;
  float acc[12][4] = {};

  for (int k0 = 0; k0 < K; k0 += 16) {
    {
      const int c = tid & 15, r = tid >> 4;
      #pragma unroll
      for (int i = 0; i < 12; i++)
        Ws[c][r + 16*i] = Wb[(long)(o0 + r + 16*i) * K + k0 + c];
      if (!XT) {
        const int pp = tid & 63, rr = tid >> 6;
        #pragma unroll
        for (int i = 0; i < 4; i++)
          Xs[rr + 4*i][pp] = Xb[(long)(k0 + rr + 4*i) * P + p0 + pp];
      } else {
        const int cc = tid & 15, pr = tid >> 4;
        #pragma unroll
        for (int i = 0; i < 4; i++)
          Xs[cc][pr + 16*i] = Xb[(long)(p0 + pr + 16*i) * K + k0 + cc];
      }
    }
    __syncthreads();
    #pragma unroll
    for (int kk = 0; kk < 16; kk++) {
      const float4 xv = *(const float4*)&Xs[kk][tx*4];
      #pragma unroll
      for (int jq = 0; jq < 3; jq++) {
        const float4 a = *(const float4*)&Ws[kk][ty*12 + jq*4];
        acc[jq*4+0][0] += a.x*xv.x; acc[jq*4+0][1] += a.x*xv.y; acc[jq*4+0][2] += a.x*xv.z; acc[jq*4+0][3] += a.x*xv.w;
        acc[jq*4+1][0] += a.y*xv.x; acc[jq*4+1][1] += a.y*xv.y; acc[jq*4+1][2] += a.y*xv.z; acc[jq*4+1][3] += a.y*xv.w;
        acc[jq*4+2][0] += a.z*xv.x; acc[jq*4+2][1] += a.z*xv.y; acc[jq*4+2][2] += a.z*xv.z; acc[jq*4+2][3] += a.z*xv.w;
        acc[jq*4+3][0] += a.w*xv.x; acc[jq*4+3][1] += a.w*xv.y; acc[jq*4+3][2] += a.w*xv.z; acc[jq*4+3][3] += a.w*xv.w;
      }
    }
    __syncthreads();
  }

  #pragma unroll
  for (int i = 0; i < 12; i++) {
    const int o = o0 + ty*12 + i;
    const long base = (long)o * P + p0 + tx*4;
    float4 r = make_float4(acc[i][0], acc[i][1], acc[i][2], acc[i][3]);
    if (EPI == 1) {
      const float4 xr = *(const float4*)&Xb[base];
      r.x += xr.x; r.y += xr.y; r.z += xr.z; r.w += xr.w;
    }
    if (EPI == 2) {
      float gv[4];
      #pragma unroll
      for (int j = 0; j < 4; j++) {
        const int p  = p0 + tx*4 + j;
        const int y  = p >> 8,        x  = p & 255;
        const int yy = (y + 252) & 255, xx = (x + 252) & 255;   // roll(+4,+4)
        const int win = b*1024 + (yy>>3)*32 + (xx>>3);
        const int n   = ((yy&7)<<3) | (xx&7);
        gv[j] = G1[(long)o * 262144 + win*64 + n];
      }
      r.x += gv[0]; r.y += gv[1]; r.z += gv[2]; r.w += gv[3];
    }
    *(float4*)&Ob[base] = r;
  }
}

// ---------------------------------------------------------------------------
// Depthwise 3x3, SAME padding. grid(Hh, B*Cc), block(Ww)
// ---------------------------------------------------------------------------
__global__ void dwconv_k(const float* __restrict__ in, const float* __restrict__ wd,
                         float* __restrict__ out, int Cc, int Hh, int Ww)
{
  const int y = blockIdx.x, bc = blockIdx.y;
  const int x = threadIdx.x;
  const int c = bc % Cc;
  const float* w9 = wd + c*9;
  const float* ip = in + (long)bc * Hh * Ww;
  float s = 0.f;
  #pragma unroll
  for (int dy = 0; dy < 3; dy++) {
    const int yy = y + dy - 1;
    if (yy < 0 || yy >= Hh) continue;
    const float* row = ip + (long)yy * Ww;
    #pragma unroll
    for (int dx = 0; dx < 3; dx++) {
      const int xx = x + dx - 1;
      if (xx >= 0 && xx < Ww) s += w9[dy*3+dx] * row[xx];
    }
  }
  out[(long)bc * Hh * Ww + (long)y * Ww + x] = s;
}

// ---------------------------------------------------------------------------
// Depthwise 3x3 on the window-shuffled q1 image (16,192,128,128), gathering
// from the linear conv1x1 output (4,192,256,256). grid(128, 16*192), block(128)
// ---------------------------------------------------------------------------
__global__ void dwshuf_k(const float* __restrict__ in, const float* __restrict__ wd,
                         float* __restrict__ out)
{
  const int y1 = blockIdx.x, bc = blockIdx.y;
  const int x1 = threadIdx.x;
  const int c = bc % 192, Bp = bc / 192;
  const int bq = Bp >> 2, q3 = Bp & 3;
  const float* w9 = wd + c*9;
  const float* ip = in + ((long)bq*192 + c) * 65536;
  float s = 0.f;
  #pragma unroll
  for (int dy = 0; dy < 3; dy++) {
    const int yy = y1 + dy - 1;
    if (yy < 0 || yy >= 128) continue;
    const int hi = yy >> 3, ry = yy & 7;
    const int wy = q3*8 + (hi >> 1);
    #pragma unroll
    for (int dx = 0; dx < 3; dx++) {
      const int xx = x1 + dx - 1;
      if (xx < 0 || xx >= 128) continue;
      const int wi = xx >> 3, rx = xx & 7;
      const int wx = ((hi & 1) << 4) + wi;
      s += w9[dy*3+dx] * ip[(wy*8 + ry)*256 + wx*8 + rx];
    }
  }
  out[(long)bc * 16384 + y1*128 + x1] = s;
}

// ---------------------------------------------------------------------------
// AvgPool2d(2,2): (4,192,256,256) -> (4,192,128,128). grid(128, 768), block(128)
// ---------------------------------------------------------------------------
__global__ void avgpool_k(const float* __restrict__ in, float* __restrict__ out)
{
  const int y = blockIdx.x, bc = blockIdx.y;
  const int x = threadIdx.x;
  const float* ip = in + (long)bc*65536 + (2*y)*256 + 2*x;
  out[(long)bc*16384 + y*128 + x] = 0.25f * (ip[0] + ip[1] + ip[256] + ip[257]);
}

// ---------------------------------------------------------------------------
// Branch0 gram + sum-of-squares: G[b,h,c,d] = sum_n q[c,n]k[d,n] (split-K atomics)
// nrm[0..767] = sum q^2 per (b, h*32+c); nrm[768..1535] = sum k^2.
// grid(64, 6, 4), block(64)
// ---------------------------------------------------------------------------
__global__ __launch_bounds__(64)
void gram_k(const float* __restrict__ q, const float* __restrict__ k,
            float* __restrict__ G, float* __restrict__ nrm)
{
  const int chunk = blockIdx.x, h = blockIdx.y, b = blockIdx.z;
  const long base = ((long)b*192 + h*32) * 65536 + chunk*1024;
  __shared__ float Qs[64][36];
  __shared__ float Ks[64][36];
  const int tid = threadIdx.x;
  const int ty = tid >> 3, tx = tid & 7;
  const int cc = tid & 31;
  float acc[4][4] = {};
  float ssq = 0.f;

  for (int t = 0; t < 16; t++) {
    __syncthreads();
    #pragma unroll 8
    for (int c = 0; c < 32; c++) {
      Qs[tid][c] = q[base + (long)c*65536 + t*64 + tid];
      Ks[tid][c] = k[base + (long)c*65536 + t*64 + tid];
    }
    __syncthreads();
    {
      const float (*S)[36] = (tid < 32) ? Qs : Ks;
      float lo = 0.f;
      #pragma unroll 16
      for (int n = 0; n < 64; n++) { const float v = S[n][cc]; lo += v*v; }
      ssq += lo;
    }
    #pragma unroll 8
    for (int n = 0; n < 64; n++) {
      const float4 a = *(const float4*)&Qs[n][ty*4];
      const float4 v = *(const float4*)&Ks[n][tx*4];
      acc[0][0] += a.x*v.x; acc[0][1] += a.x*v.y; acc[0][2] += a.x*v.z; acc[0][3] += a.x*v.w;
      acc[1][0] += a.y*v.x; acc[1][1] += a.y*v.y; acc[1][2] += a.y*v.z; acc[1][3] += a.y*v.w;
      acc[2][0] += a.z*v.x; acc[2][1] += a.z*v.y; acc[2][2] += a.z*v.z; acc[2][3] += a.z*v.w;
      acc[3][0] += a.w*v.x; acc[3][1] += a.w*v.y; acc[3][2] += a.w*v.z; acc[3][3] += a.w*v.w;
    }
  }
  float* Gp = G + (long)(b*6 + h) * 1024;
  #pragma unroll
  for (int i = 0; i < 4; i++)
    #pragma unroll
    for (int j = 0; j < 4; j++)
      atomicAdd(&Gp[(ty*4 + i)*32 + tx*4 + j], acc[i][j]);
  atomicAdd(&nrm[(tid < 32 ? 0 : 768) + b*192 + h*32 + cc], ssq);
}

// ---------------------------------------------------------------------------
// Branch0 softmax over d of G/(|q||k|)*temp0. grid(24), block(32)
// ---------------------------------------------------------------------------
__global__ void softmax0_k(const float* __restrict__ G, const float* __restrict__ nrm,
                           const float* __restrict__ temp0, float* __restrict__ attn)
{
  const int bh = blockIdx.x;
  const int b = bh / 6, h = bh % 6;
  const int c = threadIdx.x;
  __shared__ float nks[32];
  nks[c] = fmaxf(sqrtf(nrm[768 + b*192 + h*32 + c]), 1e-12f);
  __syncthreads();
  const float nq = fmaxf(sqrtf(nrm[b*192 + h*32 + c]), 1e-12f);
  const float t = temp0[h];
  const float* g = G + (long)bh*1024 + c*32;
  float v[32];
  float mx = -1e30f;
  #pragma unroll
  for (int d = 0; d < 32; d++) { v[d] = g[d] / (nq * nks[d]) * t; mx = fmaxf(mx, v[d]); }
  float s = 0.f;
  #pragma unroll
  for (int d = 0; d < 32; d++) { v[d] = __expf(v[d] - mx); s += v[d]; }
  const float inv = 1.f / s;
  float* a = attn + (long)bh*1024 + c*32;
  #pragma unroll
  for (int d = 0; d < 32; d++) a[d] = v[d] * inv;
}

// ---------------------------------------------------------------------------
// M0[b,o,h*32+d] = sum_c Wproj0[o,h*32+c] * attn[b,h,c,d]. grid(192,4), block(192)
// ---------------------------------------------------------------------------
__global__ void m0_k(const float* __restrict__ Wp, const float* __restrict__ attn,
                     float* __restrict__ M0)
{
  const int o = blockIdx.x, b = blockIdx.y, m = threadIdx.x;
  const int h = m >> 5, d = m & 31;
  const float* a = attn + (long)(b*6 + h)*1024 + d;
  const float* w = Wp + (long)o*192 + h*32;
  float s = 0.f;
  #pragma unroll
  for (int c = 0; c < 32; c++) s += w[c] * a[c*32];
  M0[((long)b*192 + o)*192 + m] = s;
}

// ---------------------------------------------------------------------------
// Shifted-window cosine attention. 4 q-windows sharing one kv-window per
// block: 256 threads = 4 waves, wave w owns q-window win = kwin*4 + w.
// K/V/nkinv/rpb live once in LDS, shared by the 4 waves.
// Register-cheap fixups (vs round-1): reciprocal k-norms (no per-score
// divide), ballot-register mask with uniform edge-skip (no cnt[] LDS), and
// k-norm partials accumulated during staging. One q-window per wave keeps
// VGPR at ~112 (round-2's 2-windows/wave spilled: VGPR 256, 1.5 GB scratch).
// q1s: (16,192,128,128) shuffled q (post-dwconv); kv1d: (4,384,128,128).
// grid(1024, 6), block(256)
// ---------------------------------------------------------------------------
__global__ __launch_bounds__(256)
void wattn_k(const float* __restrict__ q1s, const float* __restrict__ kv1d,
             const float* __restrict__ rpb_table, const float* __restrict__ temp1,
             float* __restrict__ out1)
{
  const int kwin = blockIdx.x, head = blockIdx.y;
  const int tid = threadIdx.x;
  const int w = tid >> 6, lane = tid & 63;
  const int win = kwin*4 + w;

  const int qimg = win >> 8, hi = (win >> 4) & 15, wi = win & 15;
  const int kb = kwin >> 8, khi = (kwin >> 4) & 15, kwi = kwin & 15;
  const int mw  = kwin & 255, mhi = mw >> 4, mwi = mw & 15;

  __shared__ float Ks[32][64];
  __shared__ float Vs[32][64];
  __shared__ float nkp[4][64];
  __shared__ float nkinv_s[64];
  __shared__ float rpbh[226];

  const int r  = lane >> 3, s_ = lane & 7;
  const int qy = (hi*8  + r + 4) & 127, qx = (wi*8  + s_ + 4) & 127;
  const int ky = (khi*8 + r + 4) & 127, kx = (kwi*8 + s_ + 4) & 127;

  const long qbase = ((long)qimg*192 + head*32) * 16384;
  const long kbase = ((long)kb*384  + head*32) * 16384;
  const long qoff = (long)qy*128 + qx;
  const long koff = (long)ky*128 + kx;

  // cooperative K/V staging: wave w loads channels w*8 .. w*8+7;
  // k-norm partials accumulated for free while values sit in registers
  {
    float kk = 0.f;
    #pragma unroll
    for (int i = 0; i < 8; i++) {
      const int ch = w*8 + i;
      const float kvl = kv1d[kbase + (long)ch*16384 + koff];
      Ks[ch][lane] = kvl;
      kk += kvl*kvl;
      Vs[ch][lane] = kv1d[kbase + (long)(192 + ch)*16384 + koff];
    }
    nkp[w][lane] = kk;
  }
  for (int i = tid; i < 225; i += 256) rpbh[i] = rpb_table[i*6 + head];

  // Q straight to registers (each wave its own window)
  float qreg[32];
  float nq = 0.f;
  #pragma unroll
  for (int ch = 0; ch < 32; ch++) {
    qreg[ch] = q1s[qbase + (long)ch*16384 + qoff];
    nq += qreg[ch]*qreg[ch];
  }

  // mask bitmask: register-only; uniform branch skipped by 87% of blocks.
  // bit m of bm set <=> position m is in my region (lane <-> position n).
  const bool edge = (mhi == 15) || (mwi == 15);
  unsigned long long bm = ~0ull;
  if (edge) {
    const int gy = mhi*8 + r, gx = mwi*8 + s_;
    const int yid = (gy < 120) ? 0 : ((gy < 124) ? 1 : 2);
    const int xid = (gx < 120) ? 0 : ((gx < 124) ? 1 : 2);
    const int myc = yid*3 + xid;
    #pragma unroll
    for (int g = 0; g < 9; g++) {
      const unsigned long long mgm = __ballot(myc == g);
      if (myc == g) bm = mgm;
    }
  }

  __syncthreads();   // Ks/Vs/nkp/rpbh visible

  if (tid < 64)
    nkinv_s[lane] = 1.f / fmaxf(sqrtf(nkp[0][lane] + nkp[1][lane] +
                                      nkp[2][lane] + nkp[3][lane]), 1e-12f);

  // QK^T (broadcast Ks reads; overlaps wave0's nkinv computation)
  float sc[64];
  #pragma unroll
  for (int mg = 0; mg < 16; mg++) {
    float ax = 0.f, ay = 0.f, az = 0.f, aw = 0.f;
    #pragma unroll
    for (int ch = 0; ch < 32; ch++) {
      const float4 k4 = *(const float4*)&Ks[ch][mg*4];
      const float qv = qreg[ch];
      ax += qv*k4.x; ay += qv*k4.y; az += qv*k4.z; aw += qv*k4.w;
    }
    sc[mg*4+0] = ax; sc[mg*4+1] = ay; sc[mg*4+2] = az; sc[mg*4+3] = aw;
  }

  __syncthreads();   // nkinv_s ready

  const float sA = temp1[head] / fmaxf(sqrtf(nq), 1e-12f);
  const int ib = (r + 7)*15 + (s_ + 7);
  if (edge) {
    #pragma unroll
    for (int m = 0; m < 64; m++) {
      const int rm = m >> 3, sm = m & 7;
      float u = rpbh[ib - rm*15 - sm];
      u += ((bm >> m) & 1ull) ? 0.f : -100.f;
      sc[m] = sc[m] * nkinv_s[m] * sA + u;
    }
  } else {
    #pragma unroll
    for (int m = 0; m < 64; m++) {
      const int rm = m >> 3, sm = m & 7;
      sc[m] = sc[m] * nkinv_s[m] * sA + rpbh[ib - rm*15 - sm];
    }
  }

  float mx = sc[0];
  #pragma unroll
  for (int m = 1; m < 64; m++) mx = fmaxf(mx, sc[m]);
  float sum = 0.f;
  #pragma unroll
  for (int m = 0; m < 64; m++) { sc[m] = __expf(sc[m] - mx); sum += sc[m]; }
  const float inv = 1.f / sum;

  float acc[32];
  #pragma unroll
  for (int ch = 0; ch < 32; ch++) {
    float a = 0.f;
    #pragma unroll
    for (int mg = 0; mg < 16; mg++) {
      const float4 v4 = *(const float4*)&Vs[ch][mg*4];
      a += sc[mg*4+0]*v4.x + sc[mg*4+1]*v4.y + sc[mg*4+2]*v4.z + sc[mg*4+3]*v4.w;
    }
    acc[ch] = a * inv;
  }

  float* op = out1 + ((long)win*64 + lane)*192 + head*32;
  #pragma unroll
  for (int g = 0; g < 8; g++)
    *(float4*)&op[g*4] = make_float4(acc[g*4], acc[g*4+1], acc[g*4+2], acc[g*4+3]);
}

// ---------------------------------------------------------------------------
// Buffer lifetime map:
//   U1: conv scratch -> kv1_lin(S3)+kv1d(S4) -> out1w
//   U2: q0_dw -> v0_dw (LIVE until final GEMM)
//   U3: xds(S1)+xds2(S2) -> q1s
//   d_out: q1_lin -> out1pre -> final output
// KV path runs BEFORE dwshuf so S2 is consumed before q1s overwrites U3.
// ---------------------------------------------------------------------------
extern "C" void kernel_launch(void* const* d_in, const int* in_sizes, int n_in,
                              void* d_out, int out_size, void* d_ws, size_t ws_size,
                              hipStream_t stream)
{
  (void)in_sizes; (void)n_in; (void)out_size; (void)ws_size;
  const float* x      = (const float*)d_in[0];
  const float* Wq0    = (const float*)d_in[1];
  const float* Wqdw0  = (const float*)d_in[2];
  const float* Wkv0   = (const float*)d_in[3];
  const float* Wkvdw0 = (const float*)d_in[4];
  const float* Wq1    = (const float*)d_in[5];
  const float* Wqdw1  = (const float*)d_in[6];
  const float* Wkv1   = (const float*)d_in[7];
  const float* Wkvdw1 = (const float*)d_in[8];
  const float* Wproj0 = (const float*)d_in[9];
  const float* Wproj1 = (const float*)d_in[10];
  const float* temp0  = (const float*)d_in[11];
  const float* temp1  = (const float*)d_in[12];
  const float* rpbt   = (const float*)d_in[13];
  const float* Wds    = (const float*)d_in[14];

  char* ws = (char*)d_ws;
  const long UB = 201326592L;              // 4*192*65536*4 bytes
  float* U1 = (float*)(ws);
  float* U2 = (float*)(ws + UB);
  float* U3 = (float*)(ws + 2*UB);
  char* tiny = ws + 3*UB;
  float* G     = (float*)(tiny);           // 4*6*32*32
  float* nrm   = (float*)(tiny + 98304);   // 2*768
  float* attn0 = (float*)(tiny + 104448);  // 4*6*32*32
  float* M0    = (float*)(tiny + 202752);  // 4*192*192

  float* S1   = U3;                                  // xds   (4,192,128,128)
  float* S2   = (float*)((char*)U3 + 50331648);      // xds2
  float* S3   = U1;                                  // kv1_lin (4,384,128,128)
  float* S4   = (float*)((char*)U1 + 100663296);     // kv1d
  float* q1lin = (float*)d_out;                      // (4,192,256,256) scratch
  float* q1s  = U3;                                  // (16,192,128,128) after S1/S2 dead
  float* out1pre = (float*)d_out;                    // (4096*64,192) scratch in d_out
  float* out1w   = U1;                               // (192, 262144) after S3/S4 dead

  const long XS  = 192L * 65536;
  const long XS2 = 192L * 16384;

  // ---- branch 0 ----
  gemm_k<0,false><<<dim3(1024,1,4), 256, 0, stream>>>(Wq0, x, U1, nullptr, 192, 65536, 0L, XS, XS);
  dwconv_k<<<dim3(256,768), 256, 0, stream>>>(U1, Wqdw0, U2, 192, 256, 256);            // q0_dw -> U2
  gemm_k<0,false><<<dim3(1024,1,4), 256, 0, stream>>>(Wkv0, x, U1, nullptr, 192, 65536, 0L, XS, XS);
  dwconv_k<<<dim3(256,768), 256, 0, stream>>>(U1, Wkvdw0, U3, 192, 256, 256);           // k0_dw -> U3
  hipMemsetAsync(G, 0, 104448, stream);                                                 // G + nrm
  gram_k<<<dim3(64,6,4), 64, 0, stream>>>(U2, U3, G, nrm);
  softmax0_k<<<24, 32, 0, stream>>>(G, nrm, temp0, attn0);
  m0_k<<<dim3(192,4), 192, 0, stream>>>(Wproj0, attn0, M0);
  gemm_k<0,false><<<dim3(1024,1,4), 256, 0, stream>>>(Wkv0 + 192*192, x, U1, nullptr, 192, 65536, 0L, XS, XS);
  dwconv_k<<<dim3(256,768), 256, 0, stream>>>(U1, Wkvdw0 + 192*9, U2, 192, 256, 256);   // v0_dw -> U2 (live to end)

  // ---- branch 1: KV path first (consumes S2 before q1s overwrites U3) ----
  avgpool_k<<<dim3(128,768), 128, 0, stream>>>(x, S1);
  gemm_k<1,false><<<dim3(256,1,4), 256, 0, stream>>>(Wds, S1, S2, nullptr, 192, 16384, 0L, XS2, XS2);
  gemm_k<0,false><<<dim3(256,2,4), 256, 0, stream>>>(Wkv1, S2, S3, nullptr, 192, 16384, 0L, XS2, 384L*16384);
  dwconv_k<<<dim3(128,1536), 128, 0, stream>>>(S3, Wkvdw1, S4, 384, 128, 128);           // kv1d -> S4

  // ---- branch 1: Q path ----
  gemm_k<0,false><<<dim3(1024,1,4), 256, 0, stream>>>(Wq1, x, q1lin, nullptr, 192, 65536, 0L, XS, XS);
  dwshuf_k<<<dim3(128,3072), 128, 0, stream>>>(q1lin, Wqdw1, q1s);                        // q1s -> U3 (full)
  wattn_k<<<dim3(1024,6), 256, 0, stream>>>(q1s, S4, rpbt, temp1, out1pre);               // -> d_out
  gemm_k<0,true><<<dim3(4096,1,1), 256, 0, stream>>>(Wproj1, out1pre, out1w, nullptr, 192, 262144, 0L, 0L, 0L);

  // ---- final: out = M0 @ v0_dw + gathered out1 ----
  gemm_k<2,false><<<dim3(1024,1,4), 256, 0, stream>>>(M0, U2, (float*)d_out, out1w, 192, 65536, 36864L, XS, XS);
}